// Round 4
// baseline (173.896 us; speedup 1.0000x reference)
//
#include <hip/hip_runtime.h>
#include <hip/hip_bf16.h>

// Hard-batch-mining triplet loss, B=4096, D=2048, NCLS=64, margin=0.3.
// prep (fp32->bf16 + row norms + init) -> gram (SYMMETRIC triangular bf16 MFMA
// GEMM, 2-phase software-pipelined LDS double-buffer, fused distance/mask +
// dual row/col hardest-pos/neg reduction) -> loss.
// Symmetry: only tiles bx>=by computed (528 of 1024); off-diagonal tiles
// update BOTH row-i and col-j reductions (atomics are idempotent for max/min).
// Pipeline per K-step: stage(next) -> compute(cur) -> __syncthreads() —
// one full-drain barrier/step; prefetch hides under MFMA (latency-bound fix).
// XCD swizzle: 528%8==0 -> bijective chunking, A-panels L2-resident per XCD.

typedef __attribute__((ext_vector_type(8))) short short8;
typedef __attribute__((ext_vector_type(4))) float f32x4;
using bf16 = __hip_bfloat16;

#define BN_ROWS 4096
#define D_DIM   2048
#define TILE    128
#define BK      64
#define NSTEP   (D_DIM / BK)          // 32
#define NB      (BN_ROWS / TILE)      // 32
#define NBLK    (NB * (NB + 1) / 2)   // 528
#define MARGIN  0.3f

__device__ __forceinline__ void gload16(const bf16* g, bf16* l) {
  __builtin_amdgcn_global_load_lds(
      (const __attribute__((address_space(1))) void*)g,
      (__attribute__((address_space(3))) void*)l, 16, 0, 0);
}

// ---------------- prep: convert + row norms + init reductions ----------------
__global__ __launch_bounds__(256) void prep_kernel(
    const float* __restrict__ x, bf16* __restrict__ xb, float* __restrict__ sqv,
    unsigned* __restrict__ pos, unsigned* __restrict__ neg) {
  const int row = blockIdx.x;
  const int t = threadIdx.x;
  const float4* xr = (const float4*)(x + (size_t)row * D_DIM);
  bf16* xbr = xb + (size_t)row * D_DIM;
  float s = 0.f;
  #pragma unroll
  for (int p = 0; p < 2; ++p) {
    const int idx = t + p * 256;  // float4 index, 512 per row; lane-consecutive
    float4 a = xr[idx];
    s += a.x * a.x + a.y * a.y + a.z * a.z + a.w * a.w;
    union { ushort4 v; bf16 h[4]; } u;
    u.h[0] = __float2bfloat16(a.x);
    u.h[1] = __float2bfloat16(a.y);
    u.h[2] = __float2bfloat16(a.z);
    u.h[3] = __float2bfloat16(a.w);
    *(ushort4*)(xbr + (size_t)idx * 4) = u.v;
  }
  #pragma unroll
  for (int o = 32; o; o >>= 1) s += __shfl_down(s, o, 64);
  __shared__ float red[4];
  if ((t & 63) == 0) red[t >> 6] = s;
  __syncthreads();
  if (t == 0) {
    sqv[row] = red[0] + red[1] + red[2] + red[3];
    pos[row] = 0u;           // distances >= 0; diagonal is always same-class
    neg[row] = 0x7F800000u;  // +inf
  }
}

// ---------------- gram: triangular, pipelined, dual-reduce -------------------
// 4 waves in 2x2, each 64x64 (4x4 fragments of 16x16x32). LDS [128][64] bf16
// per buffer, XOR swizzle (c16 ^= row&7) both-sides: inverse-swizzled global
// src for linear global_load_lds dest + swizzled ds_read.
__global__ __launch_bounds__(256) void gram_kernel(
    const bf16* __restrict__ xb, const float* __restrict__ sqv,
    const int* __restrict__ tgt, unsigned* __restrict__ pos,
    unsigned* __restrict__ neg) {
  __shared__ bf16 As[2][TILE * BK];
  __shared__ bf16 Bs[2][TILE * BK];
  const int t = threadIdx.x;
  const int wave = t >> 6, lane = t & 63;

  // XCD-aware bijective swizzle (528 % 8 == 0): contiguous id range per XCD.
  const int id = (blockIdx.x & 7) * (NBLK / 8) + (blockIdx.x >> 3);

  // triangular decode: id -> (by, bx), bx >= by
  int by = (int)(0.5f * (65.0f - sqrtf(4225.0f - 8.0f * (float)id)));
  while (by * NB - (by * (by - 1)) / 2 > id) --by;
  while ((by + 1) * NB - ((by + 1) * by) / 2 <= id) ++by;
  const int bx = by + (id - (by * NB - (by * (by - 1)) / 2));
  const int rowBase = by * TILE;
  const int colBase = bx * TILE;

  const int wr = wave >> 1, wc = wave & 1;
  const int lhi = lane >> 4, llo = lane & 15;

  f32x4 acc[4][4];
  #pragma unroll
  for (int m = 0; m < 4; ++m)
    #pragma unroll
    for (int n = 0; n < 4; ++n) acc[m][n] = (f32x4){0.f, 0.f, 0.f, 0.f};

  // staging: 16 chunks of 8 rows; wave w stages chunks [4w, 4w+4)
  const int srow = lane >> 3;         // row within chunk
  const int swz = (lane & 7) ^ srow;  // inverse-swizzled source c16

  auto stage = [&](int buf, int step) {
    const size_t kcol = (size_t)step * BK + (size_t)swz * 8;
    #pragma unroll
    for (int c = 0; c < 4; ++c) {
      const int chunk = wave * 4 + c;
      gload16(xb + (size_t)(rowBase + chunk * 8 + srow) * D_DIM + kcol,
              &As[buf][chunk * 512]);
      gload16(xb + (size_t)(colBase + chunk * 8 + srow) * D_DIM + kcol,
              &Bs[buf][chunk * 512]);
    }
  };

  auto compute = [&](int buf) {
    #pragma unroll
    for (int kk = 0; kk < 2; ++kk) {
      short8 af[4], bfr[4];
      #pragma unroll
      for (int m = 0; m < 4; ++m) {
        const int row = wr * 64 + m * 16 + llo;
        const int c16 = (kk * 4 + lhi) ^ (row & 7);
        af[m] = *(const short8*)(&As[buf][row * 64 + c16 * 8]);
      }
      #pragma unroll
      for (int n = 0; n < 4; ++n) {
        const int row = wc * 64 + n * 16 + llo;
        const int c16 = (kk * 4 + lhi) ^ (row & 7);
        bfr[n] = *(const short8*)(&Bs[buf][row * 64 + c16 * 8]);
      }
      #pragma unroll
      for (int m = 0; m < 4; ++m)
        #pragma unroll
        for (int n = 0; n < 4; ++n)
          acc[m][n] = __builtin_amdgcn_mfma_f32_16x16x32_bf16(
              af[m], bfr[n], acc[m][n], 0, 0, 0);
    }
  };

  // ---- 2-phase pipelined K-loop: one full-drain barrier per step ----
  stage(0, 0);
  __syncthreads();                      // prologue loads landed
  for (int step = 0; step < NSTEP - 1; ++step) {
    const int cur = step & 1;
    stage(cur ^ 1, step + 1);           // issue next-tile loads (no wait)
    compute(cur);                       // ds_read + MFMA hide load latency
    __syncthreads();                    // drain vmcnt+lgkm; handoff buffers
  }
  compute((NSTEP - 1) & 1);             // epilogue tile (no prefetch)

  // ---- fused epilogue: distance + class mask + DUAL row/col reductions ----
  // acc layout: col j = colBase+wc*64+n*16+llo, row i = rowBase+wr*64+m*16+lhi*4+r
  const float inf = __uint_as_float(0x7F800000u);
  float sqj[4];
  int tgj[4];
  #pragma unroll
  for (int n = 0; n < 4; ++n) {
    const int j = colBase + wc * 64 + n * 16 + llo;
    sqj[n] = sqv[j];
    tgj[n] = tgt[j];
  }
  float colP[4] = {0.f, 0.f, 0.f, 0.f};
  float colN[4] = {inf, inf, inf, inf};

  #pragma unroll
  for (int m = 0; m < 4; ++m) {
    #pragma unroll
    for (int r = 0; r < 4; ++r) {
      const int i = rowBase + wr * 64 + m * 16 + lhi * 4 + r;
      const float sqi = sqv[i];
      const int tgi = tgt[i];
      float pm = 0.0f, nm = inf;
      #pragma unroll
      for (int n = 0; n < 4; ++n) {
        const float g = acc[m][n][r];
        const float d2 = sqi + sqj[n] - 2.0f * g;
        const float d = sqrtf(fmaxf(d2, 1e-12f));
        if (tgj[n] == tgi) {
          pm = fmaxf(pm, d);
          colP[n] = fmaxf(colP[n], d);
        } else {
          nm = fminf(nm, d);
          colN[n] = fminf(colN[n], d);
        }
      }
      #pragma unroll
      for (int o = 1; o < 16; o <<= 1) {
        pm = fmaxf(pm, __shfl_xor(pm, o, 64));
        nm = fminf(nm, __shfl_xor(nm, o, 64));
      }
      if (llo == 0) {
        atomicMax(pos + i, __float_as_uint(pm));  // order-safe: d >= 0
        atomicMin(neg + i, __float_as_uint(nm));
      }
    }
  }
  // col-wise: reduce over lhi (lanes xor 16, 32), then one atomic per col j
  #pragma unroll
  for (int n = 0; n < 4; ++n) {
    float cp = colP[n], cn = colN[n];
    cp = fmaxf(cp, __shfl_xor(cp, 16, 64));
    cp = fmaxf(cp, __shfl_xor(cp, 32, 64));
    cn = fminf(cn, __shfl_xor(cn, 16, 64));
    cn = fminf(cn, __shfl_xor(cn, 32, 64));
    if (lane < 16) {
      const int j = colBase + wc * 64 + n * 16 + llo;
      atomicMax(pos + j, __float_as_uint(cp));
      atomicMin(neg + j, __float_as_uint(cn));
    }
  }
}

// ---------------- loss: mean(relu(d_pos - d_neg + margin)) -------------------
__global__ __launch_bounds__(1024) void loss_kernel(
    const unsigned* __restrict__ pos, const unsigned* __restrict__ neg,
    float* __restrict__ out) {
  const int t = threadIdx.x;
  float s = 0.f;
  for (int i = t; i < BN_ROWS; i += 1024) {
    const float dp = __uint_as_float(pos[i]);
    const float dn = __uint_as_float(neg[i]);
    const float v = dp - dn + MARGIN;
    s += v > 0.f ? v : 0.f;
  }
  #pragma unroll
  for (int o = 32; o; o >>= 1) s += __shfl_down(s, o, 64);
  __shared__ float red[16];
  if ((t & 63) == 0) red[t >> 6] = s;
  __syncthreads();
  if (t < 16) {
    float v = red[t];
    #pragma unroll
    for (int o = 8; o; o >>= 1) v += __shfl_down(v, o, 16);
    if (t == 0) out[0] = v * (1.0f / (float)BN_ROWS);
  }
}

extern "C" void kernel_launch(void* const* d_in, const int* in_sizes, int n_in,
                              void* d_out, int out_size, void* d_ws, size_t ws_size,
                              hipStream_t stream) {
  const float* x = (const float*)d_in[0];
  const int* tgt = (const int*)d_in[1];
  float* out = (float*)d_out;

  char* ws = (char*)d_ws;
  bf16* xb = (bf16*)ws;                                        // 16 MiB
  float* sqv = (float*)(ws + (size_t)BN_ROWS * D_DIM * 2);     // 16 KiB
  unsigned* pos = (unsigned*)((char*)sqv + BN_ROWS * 4);       // 16 KiB
  unsigned* neg = (unsigned*)((char*)pos + BN_ROWS * 4);       // 16 KiB

  prep_kernel<<<BN_ROWS, 256, 0, stream>>>(x, xb, sqv, pos, neg);
  gram_kernel<<<NBLK, 256, 0, stream>>>(xb, sqv, tgt, pos, neg);
  loss_kernel<<<1, 1024, 0, stream>>>(pos, neg, out);
}

// Round 5
// 159.330 us; speedup vs baseline: 1.0914x; 1.0914x over previous
//
#include <hip/hip_runtime.h>
#include <hip/hip_bf16.h>

// Hard-batch-mining triplet loss, B=4096, D=2048, NCLS=64, margin=0.3.
// prep (fp32->bf16 + row norms + init) -> gram (SYMMETRIC triangular bf16 MFMA
// GEMM, 8 waves/block for TLP, fused distance/mask + dual row/col
// hardest-pos/neg reduction) -> loss.
// R2-R4 evidence: throughput proportional to resident waves/SIMD (latency-
// bound, no pipe saturated), so this round doubles waves/block 4 -> 8
// (512 threads, 2x4 wave grid, each wave 64x32 output) keeping the verified
// LDS swizzle / fragment math / triangular decode / dual-reduce identical.
// Workspace: 16 MiB bf16 X + sq[4096] f32 + pos/neg[4096] uint-ordered f32.

typedef __attribute__((ext_vector_type(8))) short short8;
typedef __attribute__((ext_vector_type(4))) float f32x4;
using bf16 = __hip_bfloat16;

#define BN_ROWS 4096
#define D_DIM   2048
#define TILE    128
#define BK      64
#define NSTEP   (D_DIM / BK)          // 32
#define NB      (BN_ROWS / TILE)      // 32
#define NBLK    (NB * (NB + 1) / 2)   // 528
#define MARGIN  0.3f

__device__ __forceinline__ void gload16(const bf16* g, bf16* l) {
  __builtin_amdgcn_global_load_lds(
      (const __attribute__((address_space(1))) void*)g,
      (__attribute__((address_space(3))) void*)l, 16, 0, 0);
}

// ---------------- prep: convert + row norms + init reductions ----------------
__global__ __launch_bounds__(256) void prep_kernel(
    const float* __restrict__ x, bf16* __restrict__ xb, float* __restrict__ sqv,
    unsigned* __restrict__ pos, unsigned* __restrict__ neg) {
  const int row = blockIdx.x;
  const int t = threadIdx.x;
  const float4* xr = (const float4*)(x + (size_t)row * D_DIM);
  bf16* xbr = xb + (size_t)row * D_DIM;
  float s = 0.f;
  #pragma unroll
  for (int p = 0; p < 2; ++p) {
    const int idx = t + p * 256;  // float4 index, 512 per row; lane-consecutive
    float4 a = xr[idx];
    s += a.x * a.x + a.y * a.y + a.z * a.z + a.w * a.w;
    union { ushort4 v; bf16 h[4]; } u;
    u.h[0] = __float2bfloat16(a.x);
    u.h[1] = __float2bfloat16(a.y);
    u.h[2] = __float2bfloat16(a.z);
    u.h[3] = __float2bfloat16(a.w);
    *(ushort4*)(xbr + (size_t)idx * 4) = u.v;
  }
  #pragma unroll
  for (int o = 32; o; o >>= 1) s += __shfl_down(s, o, 64);
  __shared__ float red[4];
  if ((t & 63) == 0) red[t >> 6] = s;
  __syncthreads();
  if (t == 0) {
    sqv[row] = red[0] + red[1] + red[2] + red[3];
    pos[row] = 0u;           // distances >= 0; diagonal is always same-class
    neg[row] = 0x7F800000u;  // +inf
  }
}

// ---------------- gram: triangular, 8-wave, dual-reduce ----------------------
// 8 waves in 2x4 (wr in 0..1, wc in 0..3), each wave 64x32 output =
// 4x2 fragments of 16x16x32. LDS [128][64] bf16 per buffer, XOR swizzle
// (c16 ^= row&7) both-sides: inverse-swizzled global src for linear
// global_load_lds dest + swizzled ds_read.
__global__ __launch_bounds__(512) void gram_kernel(
    const bf16* __restrict__ xb, const float* __restrict__ sqv,
    const int* __restrict__ tgt, unsigned* __restrict__ pos,
    unsigned* __restrict__ neg) {
  __shared__ bf16 As[2][TILE * BK];
  __shared__ bf16 Bs[2][TILE * BK];
  const int t = threadIdx.x;
  const int wave = t >> 6, lane = t & 63;

  // XCD-aware bijective swizzle (528 % 8 == 0): contiguous id range per XCD.
  const int id = (blockIdx.x & 7) * (NBLK / 8) + (blockIdx.x >> 3);

  // triangular decode: id -> (by, bx), bx >= by
  int by = (int)(0.5f * (65.0f - sqrtf(4225.0f - 8.0f * (float)id)));
  while (by * NB - (by * (by - 1)) / 2 > id) --by;
  while ((by + 1) * NB - ((by + 1) * by) / 2 <= id) ++by;
  const int bx = by + (id - (by * NB - (by * (by - 1)) / 2));
  const int rowBase = by * TILE;
  const int colBase = bx * TILE;

  const int wr = wave >> 2, wc = wave & 3;
  const int lhi = lane >> 4, llo = lane & 15;

  f32x4 acc[4][2];
  #pragma unroll
  for (int m = 0; m < 4; ++m)
    #pragma unroll
    for (int n = 0; n < 2; ++n) acc[m][n] = (f32x4){0.f, 0.f, 0.f, 0.f};

  // staging: 16 chunks of 8 rows per matrix; wave w stages chunks {2w, 2w+1}
  const int srow = lane >> 3;         // row within chunk
  const int swz = (lane & 7) ^ srow;  // inverse-swizzled source c16

  auto stage = [&](int buf, int step) {
    const size_t kcol = (size_t)step * BK + (size_t)swz * 8;
    #pragma unroll
    for (int c = 0; c < 2; ++c) {
      const int chunk = wave * 2 + c;
      gload16(xb + (size_t)(rowBase + chunk * 8 + srow) * D_DIM + kcol,
              &As[buf][chunk * 512]);
      gload16(xb + (size_t)(colBase + chunk * 8 + srow) * D_DIM + kcol,
              &Bs[buf][chunk * 512]);
    }
  };

  auto compute = [&](int buf) {
    #pragma unroll
    for (int kk = 0; kk < 2; ++kk) {
      short8 af[4], bfr[2];
      #pragma unroll
      for (int m = 0; m < 4; ++m) {
        const int row = wr * 64 + m * 16 + llo;
        const int c16 = (kk * 4 + lhi) ^ (row & 7);
        af[m] = *(const short8*)(&As[buf][row * 64 + c16 * 8]);
      }
      #pragma unroll
      for (int n = 0; n < 2; ++n) {
        const int row = wc * 32 + n * 16 + llo;
        const int c16 = (kk * 4 + lhi) ^ (row & 7);
        bfr[n] = *(const short8*)(&Bs[buf][row * 64 + c16 * 8]);
      }
      #pragma unroll
      for (int m = 0; m < 4; ++m)
        #pragma unroll
        for (int n = 0; n < 2; ++n)
          acc[m][n] = __builtin_amdgcn_mfma_f32_16x16x32_bf16(
              af[m], bfr[n], acc[m][n], 0, 0, 0);
    }
  };

  // ---- 2-phase pipelined K-loop: one full-drain barrier per step ----
  stage(0, 0);
  __syncthreads();                      // prologue loads landed
  for (int step = 0; step < NSTEP - 1; ++step) {
    const int cur = step & 1;
    stage(cur ^ 1, step + 1);           // issue next-tile loads (no wait)
    compute(cur);                       // ds_read + MFMA hide load latency
    __syncthreads();                    // drain vmcnt+lgkm; handoff buffers
  }
  compute((NSTEP - 1) & 1);             // epilogue tile (no prefetch)

  // ---- fused epilogue: distance + class mask + DUAL row/col reductions ----
  // acc layout: col j = colBase+wc*32+n*16+llo, row i = rowBase+wr*64+m*16+lhi*4+r
  const float inf = __uint_as_float(0x7F800000u);
  float sqj[2];
  int tgj[2];
  #pragma unroll
  for (int n = 0; n < 2; ++n) {
    const int j = colBase + wc * 32 + n * 16 + llo;
    sqj[n] = sqv[j];
    tgj[n] = tgt[j];
  }
  float colP[2] = {0.f, 0.f};
  float colN[2] = {inf, inf};

  #pragma unroll
  for (int m = 0; m < 4; ++m) {
    #pragma unroll
    for (int r = 0; r < 4; ++r) {
      const int i = rowBase + wr * 64 + m * 16 + lhi * 4 + r;
      const float sqi = sqv[i];
      const int tgi = tgt[i];
      float pm = 0.0f, nm = inf;
      #pragma unroll
      for (int n = 0; n < 2; ++n) {
        const float g = acc[m][n][r];
        const float d2 = sqi + sqj[n] - 2.0f * g;
        const float d = sqrtf(fmaxf(d2, 1e-12f));
        if (tgj[n] == tgi) {
          pm = fmaxf(pm, d);
          colP[n] = fmaxf(colP[n], d);
        } else {
          nm = fminf(nm, d);
          colN[n] = fminf(colN[n], d);
        }
      }
      #pragma unroll
      for (int o = 1; o < 16; o <<= 1) {
        pm = fmaxf(pm, __shfl_xor(pm, o, 64));
        nm = fminf(nm, __shfl_xor(nm, o, 64));
      }
      if (llo == 0) {
        atomicMax(pos + i, __float_as_uint(pm));  // order-safe: d >= 0
        atomicMin(neg + i, __float_as_uint(nm));
      }
    }
  }
  // col-wise: reduce over lhi (lanes xor 16, 32), then one atomic per col j
  #pragma unroll
  for (int n = 0; n < 2; ++n) {
    float cp = colP[n], cn = colN[n];
    cp = fmaxf(cp, __shfl_xor(cp, 16, 64));
    cp = fmaxf(cp, __shfl_xor(cp, 32, 64));
    cn = fminf(cn, __shfl_xor(cn, 16, 64));
    cn = fminf(cn, __shfl_xor(cn, 32, 64));
    if (lane < 16) {
      const int j = colBase + wc * 32 + n * 16 + llo;
      atomicMax(pos + j, __float_as_uint(cp));
      atomicMin(neg + j, __float_as_uint(cn));
    }
  }
}

// ---------------- loss: mean(relu(d_pos - d_neg + margin)) -------------------
__global__ __launch_bounds__(1024) void loss_kernel(
    const unsigned* __restrict__ pos, const unsigned* __restrict__ neg,
    float* __restrict__ out) {
  const int t = threadIdx.x;
  float s = 0.f;
  for (int i = t; i < BN_ROWS; i += 1024) {
    const float dp = __uint_as_float(pos[i]);
    const float dn = __uint_as_float(neg[i]);
    const float v = dp - dn + MARGIN;
    s += v > 0.f ? v : 0.f;
  }
  #pragma unroll
  for (int o = 32; o; o >>= 1) s += __shfl_down(s, o, 64);
  __shared__ float red[16];
  if ((t & 63) == 0) red[t >> 6] = s;
  __syncthreads();
  if (t < 16) {
    float v = red[t];
    #pragma unroll
    for (int o = 8; o; o >>= 1) v += __shfl_down(v, o, 16);
    if (t == 0) out[0] = v * (1.0f / (float)BN_ROWS);
  }
}

extern "C" void kernel_launch(void* const* d_in, const int* in_sizes, int n_in,
                              void* d_out, int out_size, void* d_ws, size_t ws_size,
                              hipStream_t stream) {
  const float* x = (const float*)d_in[0];
  const int* tgt = (const int*)d_in[1];
  float* out = (float*)d_out;

  char* ws = (char*)d_ws;
  bf16* xb = (bf16*)ws;                                        // 16 MiB
  float* sqv = (float*)(ws + (size_t)BN_ROWS * D_DIM * 2);     // 16 KiB
  unsigned* pos = (unsigned*)((char*)sqv + BN_ROWS * 4);       // 16 KiB
  unsigned* neg = (unsigned*)((char*)pos + BN_ROWS * 4);       // 16 KiB

  prep_kernel<<<BN_ROWS, 256, 0, stream>>>(x, xb, sqv, pos, neg);
  gram_kernel<<<NBLK, 512, 0, stream>>>(xb, sqv, tgt, pos, neg);
  loss_kernel<<<1, 1024, 0, stream>>>(pos, neg, out);
}